// Round 20
// baseline (51.257 us; speedup 1.0000x reference)
//
#include <hip/hip_runtime.h>

// Problem constants (match reference)
#define XD 256
#define YD 256
#define ZD 16
#define TD 5
#define BD 2
#define NP 300000
#define CMID 8
#define VPB (XD * YD * ZD * TD)        // 5,242,880 voxels per batch
#define NVOX (BD * VPB)                // 10,485,760 total voxels
#define MAXPTS (BD * NP)               // 600,000

// Bit-packed occupancy, written DIRECTLY by atomic scatter:
//   bit index idx8 = colidx*128 + z*8 + t, colidx = (b<<16)|(x<<8)|y
// (identical format to the old pack_kernel output -> conv unchanged)
#define OCC_BYTES (BD * XD * YD * ZD)  // 2 MiB (L2-resident)
#define OCC_U128  (OCC_BYTES / 16)     // 131,072 columns

#define SCAT_BLOCKS ((MAXPTS + 255) / 256)   // 2344
#define CONV_BLOCKS 4096               // one (b, x, y-eighth) 32-col strip
#define CTHR 256                       // conv block threads (single-pass queue)
#define QCAP 512                       // 32-col strip occupancy ~142, max ~220

// ---------------------------------------------------------------------------
// Kernel 0: zero the 2 MiB bitfield (512 blocks, one uint4/thread).
// ---------------------------------------------------------------------------
__global__ __launch_bounds__(256) void zero_occ_kernel(uint4* __restrict__ occ) {
    occ[blockIdx.x * 256 + threadIdx.x] = uint4{0u, 0u, 0u, 0u};
}

// ---------------------------------------------------------------------------
// Kernel 1: scatter points -> occupancy bits via atomicOr (idempotent,
// fire-and-forget, no return value -> L2-side RMW).
// ---------------------------------------------------------------------------
__global__ __launch_bounds__(256) void scatter_kernel(
    const float4* __restrict__ pts, unsigned int* __restrict__ occ) {
    int i = blockIdx.x * 256 + threadIdx.x;
    if (i >= MAXPTS) return;
    float4 p = pts[i];
    // Match JAX exactly: floor(p / quant) (fp32 division), then clip.
    int cx = min(max((int)floorf(p.x / 0.4f), 0), XD - 1);
    int cy = min(max((int)floorf(p.y / 0.4f), 0), YD - 1);
    int cz = min(max((int)floorf(p.z / 0.4f), 0), ZD - 1);
    int ct = min(max((int)floorf(p.w / 1.0f), 0), TD - 1);
    int b  = i / NP;
    unsigned idx8 = (((unsigned)b << 23) | ((unsigned)cx << 15) |
                     ((unsigned)cy << 7) | ((unsigned)cz << 3) | (unsigned)ct);
    atomicOr(&occ[idx8 >> 5], 1u << (idx8 & 31));
}

// ---------------------------------------------------------------------------
// Kernel 2: strip conv — byte-identical to R19's proven kernel.
// Block (256 thr) owns columns (b, x, ny0..ny0+31), sole writer of its
// 10 KB output strip; single-pass queue; shared-window funnel mask-build;
// ffs over firing W0 rows in ascending (reference) order.
// ---------------------------------------------------------------------------
__global__ __launch_bounds__(CTHR) void conv_kernel(
    const ulonglong2* __restrict__ pk128,   // packed bitfield, 16 B/column
    const float* __restrict__ W0,   // (81, 1, 8)
    const float* __restrict__ b0,   // (8)
    const float* __restrict__ W1,   // (8, 1)
    const float* __restrict__ b1,   // (1)
    float4* __restrict__ out4) {
    __shared__ float w0s[81 * 12];            // 3.9 KB raw W0 rows (pad 12)
    __shared__ unsigned ccol[102 * 6];        // 2.4 KB padded column u32s
    __shared__ unsigned short queue[QCAP];    // 1 KB
    __shared__ float outt[32 * 80];           // 10 KB dense out-tile
    __shared__ unsigned wsum[2];
    __shared__ float b0s[CMID];
    __shared__ float w1s[CMID];
    __shared__ float b1sv;

    int tid = threadIdx.x;
    int s   = blockIdx.x;
    int b   = s >> 11;
    int x   = (s >> 3) & 255;
    int ny0 = (s & 7) << 5;

    // --- zero out-tile (640 float4 over 256 threads) ---
    float4* ot4 = (float4*)outt;
    float4 zf = {0.f, 0.f, 0.f, 0.f};
    for (int j = tid; j < 640; j += CTHR) ot4[j] = zf;

    // --- stage W0 rows via float4 (81 x 8 -> pad 12) ---
    if (tid < 81) {
        const float4* src = (const float4*)(W0 + tid * CMID);
        *(float4*)&w0s[tid * 12]     = src[0];
        *(float4*)&w0s[tid * 12 + 4] = src[1];
    }
    if (tid < CMID) {
        b0s[tid] = b0[tid];
        w1s[tid] = W1[tid];
    }
    if (tid == 0) b1sv = b1[0];

    // --- stage 3x34 packed columns as 6 padded u32s each:
    //     c[0]=0, c[1]=lo0, c[2]=lo1, c[3]=hi0, c[4]=hi1, c[5]=0 ---
    if (tid < 3 * 34) {
        int r   = tid / 34;         // dxi
        int cyl = tid % 34;         // local ny + 1
        int nx  = x + r - 1;
        int cy  = ny0 + cyl - 1;
        bool valid = ((unsigned)nx < XD) && ((unsigned)cy < YD);
        ulonglong2 v = pk128[(b << 16) | ((nx & 255) << 8) | (cy & 255)];
        unsigned long long lo = valid ? v.x : 0ull;
        unsigned long long hi = valid ? v.y : 0ull;
        unsigned* c = &ccol[tid * 6];
        c[0] = 0u;
        c[1] = (unsigned)lo;
        c[2] = (unsigned)(lo >> 32);
        c[3] = (unsigned)hi;
        c[4] = (unsigned)(hi >> 32);
        c[5] = 0u;
    }
    __syncthreads();

    // --- compaction on tid<128: u32 word (tid&3) of column (tid>>2) ---
    if (tid < 128) {
        unsigned w = ccol[(35 + (tid >> 2)) * 6 + 1 + (tid & 3)];
        int cnt = __popc(w);

        unsigned pre = (unsigned)cnt;     // shfl inclusive wave-scan (2 waves)
#pragma unroll
        for (int off = 1; off < 64; off <<= 1) {
            unsigned v = (unsigned)__shfl_up((int)pre, off, 64);
            if ((tid & 63) >= off) pre += v;
        }
        int wv = tid >> 6;
        if ((tid & 63) == 63) wsum[wv] = pre;
        __syncthreads();
        unsigned pos = ((wv == 1) ? wsum[0] : 0u) + pre - (unsigned)cnt;

        int cl = tid >> 2;
        int zb = (tid & 3) << 2;
        unsigned ww = w;
        while (ww) {
            int bi = __ffs(ww) - 1;
            ww &= ww - 1;
            int zz = zb + (bi >> 3);
            int tt = bi & 7;        // always < 5
            if (pos < QCAP)
                queue[pos] = (unsigned short)((cl << 7) | (zz << 3) | tt);
            ++pos;
        }
    } else {
        __syncthreads();            // match the scan's barrier
    }
    __syncthreads();
    unsigned qlen = wsum[0] + wsum[1];
    if (qlen > QCAP) qlen = QCAP;   // never fires (~220 max)

    // --- conv over compacted entries: SINGLE pass (qlen < 256) ---
    if (tid < (int)qlen) {
        int e  = queue[tid];
        int cl = e >> 7;
        int z  = (e >> 3) & 15;
        int t  = e & 7;

        // Window selector shared by all 9 columns: padded byte z+3.
        int wi = (z + 3) >> 2;            // u32 index in c[0..5]
        int sh = ((z + 3) & 3) * 8;       // bit shift within pair

        unsigned long long mpA = 0ull;    // fire mask rows 0..62
        unsigned mpB = 0u;                // rows 63..80
#pragma unroll
        for (int dxi = 0; dxi < 3; ++dxi) {
#pragma unroll
            for (int dyi = 0; dyi < 3; ++dyi) {
                const unsigned* c = &ccol[(dxi * 34 + cl + dyi) * 6 + wi];
                unsigned lo32 = c[0];
                unsigned hi32 = c[1];
                unsigned w32 = (unsigned)(((((unsigned long long)hi32) << 32)
                                           | lo32) >> sh);   // v_alignbit
                unsigned qw = ((w32 & 0xffffffu) << 1) >> t;
                unsigned nine = (qw & 7u) | (((qw >> 8) & 7u) << 3) |
                                (((qw >> 16) & 7u) << 6);
                int c9 = dxi * 3 + dyi;
                if (c9 < 7) mpA |= (unsigned long long)nine << (9 * c9);
                else if (c9 == 7) mpB |= nine;
                else mpB |= nine << 9;
            }
        }

        // ffs over firing W0 rows; ascending = reference accumulation order.
        float4 h0 = zf, h1 = zf;
        while (mpA) {
            int j = __ffsll(mpA) - 1;
            mpA &= mpA - 1;
            const float4* row = (const float4*)&w0s[j * 12];
            h0 += row[0];
            h1 += row[1];
        }
        while (mpB) {
            int j = __ffs(mpB) - 1;
            mpB &= mpB - 1;
            const float4* row = (const float4*)&w0s[(63 + j) * 12];
            h0 += row[0];
            h1 += row[1];
        }

        float hc[CMID] = {h0.x, h0.y, h0.z, h0.w, h1.x, h1.y, h1.z, h1.w};
        float o = 0.0f;
#pragma unroll
        for (int c = 0; c < CMID; ++c) {
            float v = 0.5f * hc[c] + b0s[c];   // grid value is exactly 0.5
            v = v > 0.0f ? v : 0.0f;           // relu
            o += v * w1s[c];
        }
        outt[cl * 80 + z * 5 + t] = o + b1sv;
    }
    __syncthreads();

    // --- dense coalesced store of the whole strip (sole writer) ---
    const float4* src = (const float4*)outt;
    float4* dst = out4 + ((size_t)b * (VPB / 4)) + (size_t)(x * YD + ny0) * 20;
    for (int j = tid; j < 640; j += CTHR) dst[j] = src[j];
}

extern "C" void kernel_launch(void* const* d_in, const int* in_sizes, int n_in,
                              void* d_out, int out_size, void* d_ws, size_t ws_size,
                              hipStream_t stream) {
    const float4* pts = (const float4*)d_in[0];
    const float* W0   = (const float*)d_in[1];
    const float* b0   = (const float*)d_in[2];
    const float* W1   = (const float*)d_in[3];
    const float* b1   = (const float*)d_in[4];
    unsigned int* occ = (unsigned int*)d_ws;   // 2 MiB bitfield

    zero_occ_kernel<<<OCC_U128 / 256, 256, 0, stream>>>((uint4*)occ);
    scatter_kernel<<<SCAT_BLOCKS, 256, 0, stream>>>(pts, occ);
    conv_kernel<<<CONV_BLOCKS, 256, 0, stream>>>(
        (const ulonglong2*)occ, W0, b0, W1, b1, (float4*)d_out);
}

// Round 21
// 45.409 us; speedup vs baseline: 1.1288x; 1.1288x over previous
//
#include <hip/hip_runtime.h>

// Problem constants (match reference)
#define XD 256
#define YD 256
#define ZD 16
#define TD 5
#define BD 2
#define NP 300000
#define CMID 8
#define VPB (XD * YD * ZD * TD)        // 5,242,880 voxels per batch
#define NVOX (BD * VPB)                // 10,485,760 total voxels
#define MAXPTS (BD * NP)               // 600,000

// Byte-per-voxel occupancy grid (scatter target; no atomics):
//   occ8[(colidx << 7) | (z << 3) | t], colidx = (b<<16)|(x<<8)|y
#define OCC8_BYTES (BD * XD * YD * ZD * 8)   // 16 MiB
#define OCC8_U128  (OCC8_BYTES / 16)         // 1,048,576
// Packed bitfield (pack output; conv input): 16 B/column, bit (z*8+t).
#define NCOL   (BD * XD * YD)                // 131,072 columns

#define SCAT_BLOCKS ((MAXPTS + 255) / 256)   // 2344
#define CONV_BLOCKS 4096               // one (b, x, y-eighth) 32-col strip
#define CTHR 512                       // conv threads: 2 lanes per entry
#define QCAP 512                       // 32-col strip occupancy ~142, max ~220

// ---------------------------------------------------------------------------
// Kernel 0: zero the 16 MiB byte grid.
// ---------------------------------------------------------------------------
__global__ __launch_bounds__(256) void zero_kernel(uint4* __restrict__ occ) {
    int i = blockIdx.x * 256 + threadIdx.x;
    uint4 z = {0u, 0u, 0u, 0u};
    for (int j = i; j < OCC8_U128; j += 2048 * 256) occ[j] = z;
}

// ---------------------------------------------------------------------------
// Kernel 1: scatter points -> occupancy bytes (plain stores, NO atomics;
// R20 proved atomicOr costs ~28 us vs ~16.5 for this whole front-end).
// ---------------------------------------------------------------------------
__global__ __launch_bounds__(256) void scatter_kernel(
    const float4* __restrict__ pts, unsigned char* __restrict__ occ8) {
    int i = blockIdx.x * 256 + threadIdx.x;
    if (i >= MAXPTS) return;
    float4 p = pts[i];
    // Match JAX exactly: floor(p / quant) (fp32 division), then clip.
    int cx = min(max((int)floorf(p.x / 0.4f), 0), XD - 1);
    int cy = min(max((int)floorf(p.y / 0.4f), 0), YD - 1);
    int cz = min(max((int)floorf(p.z / 0.4f), 0), ZD - 1);
    int ct = min(max((int)floorf(p.w / 1.0f), 0), TD - 1);
    int b  = i / NP;
    unsigned a = (((unsigned)b << 23) | ((unsigned)cx << 15) |
                  ((unsigned)cy << 7) | ((unsigned)cz << 3) | (unsigned)ct);
    occ8[a] = 1;
}

// LSB-gather: u64 of 8 bytes (each 0 or 1) -> 8-bit mask (byte j -> bit j).
__device__ __forceinline__ unsigned pack8(unsigned long long v) {
    v |= v >> 7;
    v |= v >> 14;
    v |= v >> 28;
    return (unsigned)v & 0xffu;
}

// ---------------------------------------------------------------------------
// Kernel 2: pack byte grid -> 2 MiB bitfield (fully coalesced both sides).
// ---------------------------------------------------------------------------
__global__ __launch_bounds__(256) void pack_kernel(
    const ulonglong2* __restrict__ occ16, unsigned short* __restrict__ pk) {
    int j = blockIdx.x * 256 + threadIdx.x;   // grid covers OCC8_U128 exactly
    ulonglong2 v = occ16[j];
    pk[j] = (unsigned short)(pack8(v.x) | (pack8(v.y) << 8));
}

// ---------------------------------------------------------------------------
// Kernel 3: strip conv (R19 skeleton, 512 threads). Block owns columns
// (b, x, ny0..ny0+31), sole writer of its 10 KB output strip.
// CHANGE vs R19: TWO lanes per entry. Each lane-pair builds the 81-bit fire
// mask; lane-even iterates rows 0..39, lane-odd rows 40..80 (halves the
// serial LDS-dependent ffs chain); combine via shfl_xor(1).
// ---------------------------------------------------------------------------
__global__ __launch_bounds__(CTHR) void conv_kernel(
    const ulonglong2* __restrict__ pk128,   // packed bitfield, 16 B/column
    const float* __restrict__ W0,   // (81, 1, 8)
    const float* __restrict__ b0,   // (8)
    const float* __restrict__ W1,   // (8, 1)
    const float* __restrict__ b1,   // (1)
    float4* __restrict__ out4) {
    __shared__ float w0s[81 * 12];            // 3.9 KB raw W0 rows (pad 12)
    __shared__ unsigned ccol[102 * 6];        // 2.4 KB padded column u32s
    __shared__ unsigned short queue[QCAP];    // 1 KB
    __shared__ float outt[32 * 80];           // 10 KB dense out-tile
    __shared__ unsigned wsum[2];
    __shared__ float b0s[CMID];
    __shared__ float w1s[CMID];
    __shared__ float b1sv;

    int tid = threadIdx.x;
    int s   = blockIdx.x;
    int b   = s >> 11;
    int x   = (s >> 3) & 255;
    int ny0 = (s & 7) << 5;

    // --- zero out-tile (640 float4 over 512 threads) ---
    float4* ot4 = (float4*)outt;
    float4 zf = {0.f, 0.f, 0.f, 0.f};
    for (int j = tid; j < 640; j += CTHR) ot4[j] = zf;

    // --- stage W0 rows via float4 (81 x 8 -> pad 12) ---
    if (tid < 81) {
        const float4* src = (const float4*)(W0 + tid * CMID);
        *(float4*)&w0s[tid * 12]     = src[0];
        *(float4*)&w0s[tid * 12 + 4] = src[1];
    }
    if (tid < CMID) {
        b0s[tid] = b0[tid];
        w1s[tid] = W1[tid];
    }
    if (tid == 0) b1sv = b1[0];

    // --- stage 3x34 packed columns as 6 padded u32s each:
    //     c[0]=0, c[1]=lo0, c[2]=lo1, c[3]=hi0, c[4]=hi1, c[5]=0 ---
    if (tid < 3 * 34) {
        int r   = tid / 34;         // dxi
        int cyl = tid % 34;         // local ny + 1
        int nx  = x + r - 1;
        int cy  = ny0 + cyl - 1;
        bool valid = ((unsigned)nx < XD) && ((unsigned)cy < YD);
        ulonglong2 v = pk128[(b << 16) | ((nx & 255) << 8) | (cy & 255)];
        unsigned long long lo = valid ? v.x : 0ull;
        unsigned long long hi = valid ? v.y : 0ull;
        unsigned* c = &ccol[tid * 6];
        c[0] = 0u;
        c[1] = (unsigned)lo;
        c[2] = (unsigned)(lo >> 32);
        c[3] = (unsigned)hi;
        c[4] = (unsigned)(hi >> 32);
        c[5] = 0u;
    }
    __syncthreads();

    // --- compaction on tid<128: u32 word (tid&3) of column (tid>>2) ---
    if (tid < 128) {
        unsigned w = ccol[(35 + (tid >> 2)) * 6 + 1 + (tid & 3)];
        int cnt = __popc(w);

        unsigned pre = (unsigned)cnt;     // shfl inclusive wave-scan (2 waves)
#pragma unroll
        for (int off = 1; off < 64; off <<= 1) {
            unsigned v = (unsigned)__shfl_up((int)pre, off, 64);
            if ((tid & 63) >= off) pre += v;
        }
        int wv = tid >> 6;
        if ((tid & 63) == 63) wsum[wv] = pre;
        __syncthreads();
        unsigned pos = ((wv == 1) ? wsum[0] : 0u) + pre - (unsigned)cnt;

        int cl = tid >> 2;
        int zb = (tid & 3) << 2;
        unsigned ww = w;
        while (ww) {
            int bi = __ffs(ww) - 1;
            ww &= ww - 1;
            int zz = zb + (bi >> 3);
            int tt = bi & 7;        // always < 5
            if (pos < QCAP)
                queue[pos] = (unsigned short)((cl << 7) | (zz << 3) | tt);
            ++pos;
        }
    } else {
        __syncthreads();            // match the scan's barrier
    }
    __syncthreads();
    unsigned qlen = wsum[0] + wsum[1];
    if (qlen > QCAP) qlen = QCAP;   // never fires (~220 max)

    // --- conv: 2 lanes per entry, single pass (2*qlen <= 440 < 512) ---
    unsigned qi = (unsigned)tid >> 1;
    int half = tid & 1;
    if (qi < qlen) {
        int e  = queue[qi];
        int cl = e >> 7;
        int z  = (e >> 3) & 15;
        int t  = e & 7;

        // Window selector shared by all 9 columns: padded byte z+3.
        int wi = (z + 3) >> 2;            // u32 index in c[0..5]
        int sh = ((z + 3) & 3) * 8;       // bit shift within pair

        unsigned long long mpA = 0ull;    // fire mask rows 0..62
        unsigned mpB = 0u;                // rows 63..80
#pragma unroll
        for (int dxi = 0; dxi < 3; ++dxi) {
#pragma unroll
            for (int dyi = 0; dyi < 3; ++dyi) {
                const unsigned* c = &ccol[(dxi * 34 + cl + dyi) * 6 + wi];
                unsigned lo32 = c[0];
                unsigned hi32 = c[1];
                unsigned w32 = (unsigned)(((((unsigned long long)hi32) << 32)
                                           | lo32) >> sh);   // v_alignbit
                unsigned qw = ((w32 & 0xffffffu) << 1) >> t;
                unsigned nine = (qw & 7u) | (((qw >> 8) & 7u) << 3) |
                                (((qw >> 16) & 7u) << 6);
                int c9 = dxi * 3 + dyi;
                if (c9 < 7) mpA |= (unsigned long long)nine << (9 * c9);
                else if (c9 == 7) mpB |= nine;
                else mpB |= nine << 9;
            }
        }

        // Lane-split: even lane rows 0..39, odd lane rows 40..80.
        unsigned long long m;
        int base;
        if (half == 0) {
            m = mpA & ((1ull << 40) - 1);
            base = 0;
        } else {
            m = (mpA >> 40) | ((unsigned long long)mpB << 23);
            base = 40;
        }

        float4 h0 = zf, h1 = zf;
        while (m) {
            int j = __ffsll(m) - 1;
            m &= m - 1;
            const float4* row = (const float4*)&w0s[(base + j) * 12];
            h0 += row[0];
            h1 += row[1];
        }

        // Combine halves: even lane's (rows<40) + odd lane's (rows>=40).
        float hc[CMID] = {h0.x, h0.y, h0.z, h0.w, h1.x, h1.y, h1.z, h1.w};
#pragma unroll
        for (int c = 0; c < CMID; ++c) {
            float partner = __shfl_xor(hc[c], 1, 64);
            hc[c] += partner;       // even lane: self(<40) + partner(>=40)
        }

        if (half == 0) {
            float o = 0.0f;
#pragma unroll
            for (int c = 0; c < CMID; ++c) {
                float v = 0.5f * hc[c] + b0s[c];   // grid value exactly 0.5
                v = v > 0.0f ? v : 0.0f;           // relu
                o += v * w1s[c];
            }
            outt[cl * 80 + z * 5 + t] = o + b1sv;
        }
    }
    __syncthreads();

    // --- dense coalesced store of the whole strip (sole writer) ---
    const float4* src = (const float4*)outt;
    float4* dst = out4 + ((size_t)b * (VPB / 4)) + (size_t)(x * YD + ny0) * 20;
    for (int j = tid; j < 640; j += CTHR) dst[j] = src[j];
}

extern "C" void kernel_launch(void* const* d_in, const int* in_sizes, int n_in,
                              void* d_out, int out_size, void* d_ws, size_t ws_size,
                              hipStream_t stream) {
    const float4* pts = (const float4*)d_in[0];
    const float* W0   = (const float*)d_in[1];
    const float* b0   = (const float*)d_in[2];
    const float* W1   = (const float*)d_in[3];
    const float* b1   = (const float*)d_in[4];
    unsigned char* occ8 = (unsigned char*)d_ws;               // 16 MiB bytes
    unsigned short* pk  = (unsigned short*)((char*)d_ws + OCC8_BYTES); // 2 MiB

    zero_kernel<<<2048, 256, 0, stream>>>((uint4*)occ8);
    scatter_kernel<<<SCAT_BLOCKS, 256, 0, stream>>>(pts, occ8);
    pack_kernel<<<OCC8_U128 / 256, 256, 0, stream>>>(
        (const ulonglong2*)occ8, pk);
    conv_kernel<<<CONV_BLOCKS, CTHR, 0, stream>>>(
        (const ulonglong2*)pk, W0, b0, W1, b1, (float4*)d_out);
}

// Round 22
// 42.761 us; speedup vs baseline: 1.1987x; 1.0619x over previous
//
#include <hip/hip_runtime.h>

// Problem constants (match reference)
#define XD 256
#define YD 256
#define ZD 16
#define TD 5
#define BD 2
#define NP 300000
#define CMID 8
#define VPB (XD * YD * ZD * TD)        // 5,242,880 voxels per batch
#define NVOX (BD * VPB)                // 10,485,760 total voxels
#define MAXPTS (BD * NP)               // 600,000

// Byte-per-voxel occupancy grid (scatter target; no atomics):
//   occ8[(colidx << 7) | (z << 3) | t], colidx = (b<<16)|(x<<8)|y
#define OCC8_BYTES (BD * XD * YD * ZD * 8)   // 16 MiB
#define OCC8_U128  (OCC8_BYTES / 16)         // 1,048,576
// Packed bitfield (pack output; conv input): 16 B/column, bit (z*8+t).
#define NCOL   (BD * XD * YD)                // 131,072 columns

#define SCAT_BLOCKS ((MAXPTS + 255) / 256)   // 2344
#define CONV_BLOCKS 4096               // one (b, x, y-eighth) 32-col strip
#define CTHR 256                       // conv block threads (single-pass queue)
#define QCAP 512                       // 32-col strip occupancy ~142, max ~220

// ---------------------------------------------------------------------------
// Kernel 0: zero the 16 MiB byte grid.
// ---------------------------------------------------------------------------
__global__ __launch_bounds__(256) void zero_kernel(uint4* __restrict__ occ) {
    int i = blockIdx.x * 256 + threadIdx.x;
    uint4 z = {0u, 0u, 0u, 0u};
    for (int j = i; j < OCC8_U128; j += 2048 * 256) occ[j] = z;
}

// ---------------------------------------------------------------------------
// Kernel 1: scatter points -> occupancy bytes (plain stores, NO atomics;
// R20 proved atomicOr costs ~28 us vs ~16.5 for this whole front-end).
// ---------------------------------------------------------------------------
__global__ __launch_bounds__(256) void scatter_kernel(
    const float4* __restrict__ pts, unsigned char* __restrict__ occ8) {
    int i = blockIdx.x * 256 + threadIdx.x;
    if (i >= MAXPTS) return;
    float4 p = pts[i];
    // Match JAX exactly: floor(p / quant) (fp32 division), then clip.
    int cx = min(max((int)floorf(p.x / 0.4f), 0), XD - 1);
    int cy = min(max((int)floorf(p.y / 0.4f), 0), YD - 1);
    int cz = min(max((int)floorf(p.z / 0.4f), 0), ZD - 1);
    int ct = min(max((int)floorf(p.w / 1.0f), 0), TD - 1);
    int b  = i / NP;
    unsigned a = (((unsigned)b << 23) | ((unsigned)cx << 15) |
                  ((unsigned)cy << 7) | ((unsigned)cz << 3) | (unsigned)ct);
    occ8[a] = 1;
}

// LSB-gather: u64 of 8 bytes (each 0 or 1) -> 8-bit mask (byte j -> bit j).
__device__ __forceinline__ unsigned pack8(unsigned long long v) {
    v |= v >> 7;
    v |= v >> 14;
    v |= v >> 28;
    return (unsigned)v & 0xffu;
}

// ---------------------------------------------------------------------------
// Kernel 2: pack byte grid -> 2 MiB bitfield (fully coalesced both sides).
// ---------------------------------------------------------------------------
__global__ __launch_bounds__(256) void pack_kernel(
    const ulonglong2* __restrict__ occ16, unsigned short* __restrict__ pk) {
    int j = blockIdx.x * 256 + threadIdx.x;   // grid covers OCC8_U128 exactly
    ulonglong2 v = occ16[j];
    pk[j] = (unsigned short)(pack8(v.x) | (pack8(v.y) << 8));
}

// ---------------------------------------------------------------------------
// Kernel 3: strip conv (R19 skeleton, 256 threads). Block owns columns
// (b, x, ny0..ny0+31), sole writer of its 10 KB output strip.
// CHANGE vs R19: the ffs loop extracts up to FOUR firing rows per iteration
// (dummy slots -> zero row 81, exact +0.0f adds) so the 8 ds_read_b128s
// issue independently and pipeline -- the serial latency chain drops ~4x.
// Accumulation sequence (ascending row index) is unchanged.
// ---------------------------------------------------------------------------
__global__ __launch_bounds__(CTHR) void conv_kernel(
    const ulonglong2* __restrict__ pk128,   // packed bitfield, 16 B/column
    const float* __restrict__ W0,   // (81, 1, 8)
    const float* __restrict__ b0,   // (8)
    const float* __restrict__ W1,   // (8, 1)
    const float* __restrict__ b1,   // (1)
    float4* __restrict__ out4) {
    __shared__ float w0s[82 * 12];            // 81 rows + zero row 81 (pad 12)
    __shared__ unsigned ccol[102 * 6];        // 2.4 KB padded column u32s
    __shared__ unsigned short queue[QCAP];    // 1 KB
    __shared__ float outt[32 * 80];           // 10 KB dense out-tile
    __shared__ unsigned wsum[2];
    __shared__ float b0s[CMID];
    __shared__ float w1s[CMID];
    __shared__ float b1sv;

    int tid = threadIdx.x;
    int s   = blockIdx.x;
    int b   = s >> 11;
    int x   = (s >> 3) & 255;
    int ny0 = (s & 7) << 5;

    // --- zero out-tile (640 float4 over 256 threads) ---
    float4* ot4 = (float4*)outt;
    float4 zf = {0.f, 0.f, 0.f, 0.f};
    for (int j = tid; j < 640; j += CTHR) ot4[j] = zf;

    // --- stage W0 rows via float4 (81 x 8 -> pad 12) + zero row 81 ---
    if (tid < 81) {
        const float4* src = (const float4*)(W0 + tid * CMID);
        *(float4*)&w0s[tid * 12]     = src[0];
        *(float4*)&w0s[tid * 12 + 4] = src[1];
    } else if (tid == 81) {
        *(float4*)&w0s[81 * 12]     = zf;
        *(float4*)&w0s[81 * 12 + 4] = zf;
    }
    if (tid < CMID) {
        b0s[tid] = b0[tid];
        w1s[tid] = W1[tid];
    }
    if (tid == 0) b1sv = b1[0];

    // --- stage 3x34 packed columns as 6 padded u32s each:
    //     c[0]=0, c[1]=lo0, c[2]=lo1, c[3]=hi0, c[4]=hi1, c[5]=0 ---
    if (tid < 3 * 34) {
        int r   = tid / 34;         // dxi
        int cyl = tid % 34;         // local ny + 1
        int nx  = x + r - 1;
        int cy  = ny0 + cyl - 1;
        bool valid = ((unsigned)nx < XD) && ((unsigned)cy < YD);
        ulonglong2 v = pk128[(b << 16) | ((nx & 255) << 8) | (cy & 255)];
        unsigned long long lo = valid ? v.x : 0ull;
        unsigned long long hi = valid ? v.y : 0ull;
        unsigned* c = &ccol[tid * 6];
        c[0] = 0u;
        c[1] = (unsigned)lo;
        c[2] = (unsigned)(lo >> 32);
        c[3] = (unsigned)hi;
        c[4] = (unsigned)(hi >> 32);
        c[5] = 0u;
    }
    __syncthreads();

    // --- compaction on tid<128: u32 word (tid&3) of column (tid>>2) ---
    if (tid < 128) {
        unsigned w = ccol[(35 + (tid >> 2)) * 6 + 1 + (tid & 3)];
        int cnt = __popc(w);

        unsigned pre = (unsigned)cnt;     // shfl inclusive wave-scan (2 waves)
#pragma unroll
        for (int off = 1; off < 64; off <<= 1) {
            unsigned v = (unsigned)__shfl_up((int)pre, off, 64);
            if ((tid & 63) >= off) pre += v;
        }
        int wv = tid >> 6;
        if ((tid & 63) == 63) wsum[wv] = pre;
        __syncthreads();
        unsigned pos = ((wv == 1) ? wsum[0] : 0u) + pre - (unsigned)cnt;

        int cl = tid >> 2;
        int zb = (tid & 3) << 2;
        unsigned ww = w;
        while (ww) {
            int bi = __ffs(ww) - 1;
            ww &= ww - 1;
            int zz = zb + (bi >> 3);
            int tt = bi & 7;        // always < 5
            if (pos < QCAP)
                queue[pos] = (unsigned short)((cl << 7) | (zz << 3) | tt);
            ++pos;
        }
    } else {
        __syncthreads();            // match the scan's barrier
    }
    __syncthreads();
    unsigned qlen = wsum[0] + wsum[1];
    if (qlen > QCAP) qlen = QCAP;   // never fires (~220 max)

    // --- conv over compacted entries: SINGLE pass (qlen < 256) ---
    if (tid < (int)qlen) {
        int e  = queue[tid];
        int cl = e >> 7;
        int z  = (e >> 3) & 15;
        int t  = e & 7;

        // Window selector shared by all 9 columns: padded byte z+3.
        int wi = (z + 3) >> 2;            // u32 index in c[0..5]
        int sh = ((z + 3) & 3) * 8;       // bit shift within pair

        unsigned long long mpA = 0ull;    // fire mask rows 0..62
        unsigned mpB = 0u;                // rows 63..80
#pragma unroll
        for (int dxi = 0; dxi < 3; ++dxi) {
#pragma unroll
            for (int dyi = 0; dyi < 3; ++dyi) {
                const unsigned* c = &ccol[(dxi * 34 + cl + dyi) * 6 + wi];
                unsigned lo32 = c[0];
                unsigned hi32 = c[1];
                unsigned w32 = (unsigned)(((((unsigned long long)hi32) << 32)
                                           | lo32) >> sh);   // v_alignbit
                unsigned qw = ((w32 & 0xffffffu) << 1) >> t;
                unsigned nine = (qw & 7u) | (((qw >> 8) & 7u) << 3) |
                                (((qw >> 16) & 7u) << 6);
                int c9 = dxi * 3 + dyi;
                if (c9 < 7) mpA |= (unsigned long long)nine << (9 * c9);
                else if (c9 == 7) mpB |= nine;
                else mpB |= nine << 9;
            }
        }

        // Batch-4 ffs: up to 4 firing rows per iteration; dummies hit the
        // exact-zero row 81. Ascending order == reference accumulation order.
        float4 h0 = zf, h1 = zf;
        while (mpA) {
            int j0 = __ffsll(mpA) - 1; mpA &= mpA - 1;
            int j1 = mpA ? __ffsll(mpA) - 1 : 81; mpA &= mpA - 1;
            int j2 = mpA ? __ffsll(mpA) - 1 : 81; mpA &= mpA - 1;
            int j3 = mpA ? __ffsll(mpA) - 1 : 81; mpA &= mpA - 1;
            const float4* r0 = (const float4*)&w0s[j0 * 12];
            const float4* r1 = (const float4*)&w0s[j1 * 12];
            const float4* r2 = (const float4*)&w0s[j2 * 12];
            const float4* r3 = (const float4*)&w0s[j3 * 12];
            float4 a0 = r0[0], a1 = r0[1];
            float4 b0_ = r1[0], b1_ = r1[1];
            float4 c0 = r2[0], c1 = r2[1];
            float4 d0 = r3[0], d1 = r3[1];
            h0 += a0; h1 += a1;
            h0 += b0_; h1 += b1_;
            h0 += c0; h1 += c1;
            h0 += d0; h1 += d1;
        }
        while (mpB) {
            int j0 = __ffs(mpB) - 1; mpB &= mpB - 1;
            int j1 = mpB ? __ffs(mpB) - 1 : 18; mpB &= mpB - 1;
            const float4* r0 = (const float4*)&w0s[(63 + j0) * 12];
            const float4* r1 = (const float4*)&w0s[(63 + j1) * 12];
            float4 a0 = r0[0], a1 = r0[1];
            float4 b0_ = r1[0], b1_ = r1[1];
            h0 += a0; h1 += a1;
            h0 += b0_; h1 += b1_;
        }

        float hc[CMID] = {h0.x, h0.y, h0.z, h0.w, h1.x, h1.y, h1.z, h1.w};
        float o = 0.0f;
#pragma unroll
        for (int c = 0; c < CMID; ++c) {
            float v = 0.5f * hc[c] + b0s[c];   // grid value is exactly 0.5
            v = v > 0.0f ? v : 0.0f;           // relu
            o += v * w1s[c];
        }
        outt[cl * 80 + z * 5 + t] = o + b1sv;
    }
    __syncthreads();

    // --- dense coalesced store of the whole strip (sole writer) ---
    const float4* src = (const float4*)outt;
    float4* dst = out4 + ((size_t)b * (VPB / 4)) + (size_t)(x * YD + ny0) * 20;
    for (int j = tid; j < 640; j += CTHR) dst[j] = src[j];
}

extern "C" void kernel_launch(void* const* d_in, const int* in_sizes, int n_in,
                              void* d_out, int out_size, void* d_ws, size_t ws_size,
                              hipStream_t stream) {
    const float4* pts = (const float4*)d_in[0];
    const float* W0   = (const float*)d_in[1];
    const float* b0   = (const float*)d_in[2];
    const float* W1   = (const float*)d_in[3];
    const float* b1   = (const float*)d_in[4];
    unsigned char* occ8 = (unsigned char*)d_ws;               // 16 MiB bytes
    unsigned short* pk  = (unsigned short*)((char*)d_ws + OCC8_BYTES); // 2 MiB

    zero_kernel<<<2048, 256, 0, stream>>>((uint4*)occ8);
    scatter_kernel<<<SCAT_BLOCKS, 256, 0, stream>>>(pts, occ8);
    pack_kernel<<<OCC8_U128 / 256, 256, 0, stream>>>(
        (const ulonglong2*)occ8, pk);
    conv_kernel<<<CONV_BLOCKS, CTHR, 0, stream>>>(
        (const ulonglong2*)pk, W0, b0, W1, b1, (float4*)d_out);
}

// Round 23
// 41.475 us; speedup vs baseline: 1.2359x; 1.0310x over previous
//
#include <hip/hip_runtime.h>

// Problem constants (match reference)
#define XD 256
#define YD 256
#define ZD 16
#define TD 5
#define BD 2
#define NP 300000
#define CMID 8
#define VPB (XD * YD * ZD * TD)        // 5,242,880 voxels per batch
#define NVOX (BD * VPB)                // 10,485,760 total voxels
#define MAXPTS (BD * NP)               // 600,000

// Byte-per-voxel occupancy grid (scatter target; no atomics):
//   occ8[(colidx << 7) | (z << 3) | t], colidx = (b<<16)|(x<<8)|y
#define OCC8_BYTES (BD * XD * YD * ZD * 8)   // 16 MiB
#define OCC8_U128  (OCC8_BYTES / 16)         // 1,048,576
// Packed bitfield (pack output; conv input): 16 B/column, bit (z*8+t).
#define NCOL   (BD * XD * YD)                // 131,072 columns

#define SCAT_BLOCKS ((MAXPTS + 255) / 256)   // 2344
#define CONV_BLOCKS 2048               // 2 strips per block (4096 strips)
#define STRIPS_PER_BLOCK 2
#define CTHR 256                       // conv block threads (single-pass queue)
#define QCAP 512                       // 32-col strip occupancy ~142, max ~220

// ---------------------------------------------------------------------------
// Kernel 0: zero the 16 MiB byte grid.
// ---------------------------------------------------------------------------
__global__ __launch_bounds__(256) void zero_kernel(uint4* __restrict__ occ) {
    int i = blockIdx.x * 256 + threadIdx.x;
    uint4 z = {0u, 0u, 0u, 0u};
    for (int j = i; j < OCC8_U128; j += 2048 * 256) occ[j] = z;
}

// ---------------------------------------------------------------------------
// Kernel 1: scatter points -> occupancy bytes (plain stores, NO atomics;
// R20 proved atomicOr costs ~28 us vs ~16.5 for this whole front-end).
// ---------------------------------------------------------------------------
__global__ __launch_bounds__(256) void scatter_kernel(
    const float4* __restrict__ pts, unsigned char* __restrict__ occ8) {
    int i = blockIdx.x * 256 + threadIdx.x;
    if (i >= MAXPTS) return;
    float4 p = pts[i];
    // Match JAX exactly: floor(p / quant) (fp32 division), then clip.
    int cx = min(max((int)floorf(p.x / 0.4f), 0), XD - 1);
    int cy = min(max((int)floorf(p.y / 0.4f), 0), YD - 1);
    int cz = min(max((int)floorf(p.z / 0.4f), 0), ZD - 1);
    int ct = min(max((int)floorf(p.w / 1.0f), 0), TD - 1);
    int b  = i / NP;
    unsigned a = (((unsigned)b << 23) | ((unsigned)cx << 15) |
                  ((unsigned)cy << 7) | ((unsigned)cz << 3) | (unsigned)ct);
    occ8[a] = 1;
}

// LSB-gather: u64 of 8 bytes (each 0 or 1) -> 8-bit mask (byte j -> bit j).
__device__ __forceinline__ unsigned pack8(unsigned long long v) {
    v |= v >> 7;
    v |= v >> 14;
    v |= v >> 28;
    return (unsigned)v & 0xffu;
}

// ---------------------------------------------------------------------------
// Kernel 2: pack byte grid -> 2 MiB bitfield (fully coalesced both sides).
// ---------------------------------------------------------------------------
__global__ __launch_bounds__(256) void pack_kernel(
    const ulonglong2* __restrict__ occ16, unsigned short* __restrict__ pk) {
    int j = blockIdx.x * 256 + threadIdx.x;   // grid covers OCC8_U128 exactly
    ulonglong2 v = occ16[j];
    pk[j] = (unsigned short)(pack8(v.x) | (pack8(v.y) << 8));
}

// ---------------------------------------------------------------------------
// Kernel 3: strip conv (R19 skeleton). Block (256 thr) processes TWO
// consecutive 32-col strips, staging W0/b0/W1/b1 ONCE (halves the per-block
// fixed machinery that R18-R22 showed dominates). Per strip, the inner
// structure is byte-identical to R19: stage ccol, shfl-scan compaction,
// single-pass shared-window funnel conv, dense coalesced strip store.
// ---------------------------------------------------------------------------
__global__ __launch_bounds__(CTHR) void conv_kernel(
    const ulonglong2* __restrict__ pk128,   // packed bitfield, 16 B/column
    const float* __restrict__ W0,   // (81, 1, 8)
    const float* __restrict__ b0,   // (8)
    const float* __restrict__ W1,   // (8, 1)
    const float* __restrict__ b1,   // (1)
    float4* __restrict__ out4) {
    __shared__ float w0s[81 * 12];            // 3.9 KB raw W0 rows (pad 12)
    __shared__ unsigned ccol[102 * 6];        // 2.4 KB padded column u32s
    __shared__ unsigned short queue[QCAP];    // 1 KB
    __shared__ float outt[32 * 80];           // 10 KB dense out-tile
    __shared__ unsigned wsum[2];
    __shared__ float b0s[CMID];
    __shared__ float w1s[CMID];
    __shared__ float b1sv;

    int tid = threadIdx.x;

    // --- stage W0 rows via float4 (81 x 8 -> pad 12); once per block ---
    if (tid < 81) {
        const float4* src = (const float4*)(W0 + tid * CMID);
        *(float4*)&w0s[tid * 12]     = src[0];
        *(float4*)&w0s[tid * 12 + 4] = src[1];
    }
    if (tid < CMID) {
        b0s[tid] = b0[tid];
        w1s[tid] = W1[tid];
    }
    if (tid == 0) b1sv = b1[0];

    for (int it = 0; it < STRIPS_PER_BLOCK; ++it) {
        int s   = blockIdx.x * STRIPS_PER_BLOCK + it;
        int b   = s >> 11;
        int x   = (s >> 3) & 255;
        int ny0 = (s & 7) << 5;

        // --- zero out-tile (640 float4 over 256 threads) ---
        float4* ot4 = (float4*)outt;
        float4 zf = {0.f, 0.f, 0.f, 0.f};
        for (int j = tid; j < 640; j += CTHR) ot4[j] = zf;

        // --- stage 3x34 packed columns as 6 padded u32s each:
        //     c[0]=0, c[1]=lo0, c[2]=lo1, c[3]=hi0, c[4]=hi1, c[5]=0 ---
        if (tid < 3 * 34) {
            int r   = tid / 34;         // dxi
            int cyl = tid % 34;         // local ny + 1
            int nx  = x + r - 1;
            int cy  = ny0 + cyl - 1;
            bool valid = ((unsigned)nx < XD) && ((unsigned)cy < YD);
            ulonglong2 v = pk128[(b << 16) | ((nx & 255) << 8) | (cy & 255)];
            unsigned long long lo = valid ? v.x : 0ull;
            unsigned long long hi = valid ? v.y : 0ull;
            unsigned* c = &ccol[tid * 6];
            c[0] = 0u;
            c[1] = (unsigned)lo;
            c[2] = (unsigned)(lo >> 32);
            c[3] = (unsigned)hi;
            c[4] = (unsigned)(hi >> 32);
            c[5] = 0u;
        }
        __syncthreads();

        // --- compaction on tid<128: u32 word (tid&3) of column (tid>>2) ---
        if (tid < 128) {
            unsigned w = ccol[(35 + (tid >> 2)) * 6 + 1 + (tid & 3)];
            int cnt = __popc(w);

            unsigned pre = (unsigned)cnt;   // shfl inclusive wave-scan
#pragma unroll
            for (int off = 1; off < 64; off <<= 1) {
                unsigned v = (unsigned)__shfl_up((int)pre, off, 64);
                if ((tid & 63) >= off) pre += v;
            }
            int wv = tid >> 6;
            if ((tid & 63) == 63) wsum[wv] = pre;
            __syncthreads();
            unsigned pos = ((wv == 1) ? wsum[0] : 0u) + pre - (unsigned)cnt;

            int cl = tid >> 2;
            int zb = (tid & 3) << 2;
            unsigned ww = w;
            while (ww) {
                int bi = __ffs(ww) - 1;
                ww &= ww - 1;
                int zz = zb + (bi >> 3);
                int tt = bi & 7;        // always < 5
                if (pos < QCAP)
                    queue[pos] = (unsigned short)((cl << 7) | (zz << 3) | tt);
                ++pos;
            }
        } else {
            __syncthreads();            // match the scan's barrier
        }
        __syncthreads();
        unsigned qlen = wsum[0] + wsum[1];
        if (qlen > QCAP) qlen = QCAP;   // never fires (~220 max)

        // --- conv over compacted entries: SINGLE pass (qlen < 256) ---
        if (tid < (int)qlen) {
            int e  = queue[tid];
            int cl = e >> 7;
            int z  = (e >> 3) & 15;
            int t  = e & 7;

            // Window selector shared by all 9 columns: padded byte z+3.
            int wi = (z + 3) >> 2;            // u32 index in c[0..5]
            int sh = ((z + 3) & 3) * 8;       // bit shift within pair

            unsigned long long mpA = 0ull;    // fire mask rows 0..62
            unsigned mpB = 0u;                // rows 63..80
#pragma unroll
            for (int dxi = 0; dxi < 3; ++dxi) {
#pragma unroll
                for (int dyi = 0; dyi < 3; ++dyi) {
                    const unsigned* c = &ccol[(dxi * 34 + cl + dyi) * 6 + wi];
                    unsigned lo32 = c[0];
                    unsigned hi32 = c[1];
                    unsigned w32 = (unsigned)(((((unsigned long long)hi32) << 32)
                                               | lo32) >> sh);   // v_alignbit
                    unsigned qw = ((w32 & 0xffffffu) << 1) >> t;
                    unsigned nine = (qw & 7u) | (((qw >> 8) & 7u) << 3) |
                                    (((qw >> 16) & 7u) << 6);
                    int c9 = dxi * 3 + dyi;
                    if (c9 < 7) mpA |= (unsigned long long)nine << (9 * c9);
                    else if (c9 == 7) mpB |= nine;
                    else mpB |= nine << 9;
                }
            }

            // ffs over firing W0 rows; ascending = reference order.
            float4 h0 = zf, h1 = zf;
            while (mpA) {
                int j = __ffsll(mpA) - 1;
                mpA &= mpA - 1;
                const float4* row = (const float4*)&w0s[j * 12];
                h0 += row[0];
                h1 += row[1];
            }
            while (mpB) {
                int j = __ffs(mpB) - 1;
                mpB &= mpB - 1;
                const float4* row = (const float4*)&w0s[(63 + j) * 12];
                h0 += row[0];
                h1 += row[1];
            }

            float hc[CMID] = {h0.x, h0.y, h0.z, h0.w, h1.x, h1.y, h1.z, h1.w};
            float o = 0.0f;
#pragma unroll
            for (int c = 0; c < CMID; ++c) {
                float v = 0.5f * hc[c] + b0s[c];   // grid value exactly 0.5
                v = v > 0.0f ? v : 0.0f;           // relu
                o += v * w1s[c];
            }
            outt[cl * 80 + z * 5 + t] = o + b1sv;
        }
        __syncthreads();

        // --- dense coalesced store of the whole strip (sole writer) ---
        const float4* src = (const float4*)outt;
        float4* dst = out4 + ((size_t)b * (VPB / 4)) +
                      (size_t)(x * YD + ny0) * 20;
        for (int j = tid; j < 640; j += CTHR) dst[j] = src[j];
        __syncthreads();   // protect outt/ccol reuse by next strip
    }
}

extern "C" void kernel_launch(void* const* d_in, const int* in_sizes, int n_in,
                              void* d_out, int out_size, void* d_ws, size_t ws_size,
                              hipStream_t stream) {
    const float4* pts = (const float4*)d_in[0];
    const float* W0   = (const float*)d_in[1];
    const float* b0   = (const float*)d_in[2];
    const float* W1   = (const float*)d_in[3];
    const float* b1   = (const float*)d_in[4];
    unsigned char* occ8 = (unsigned char*)d_ws;               // 16 MiB bytes
    unsigned short* pk  = (unsigned short*)((char*)d_ws + OCC8_BYTES); // 2 MiB

    zero_kernel<<<2048, 256, 0, stream>>>((uint4*)occ8);
    scatter_kernel<<<SCAT_BLOCKS, 256, 0, stream>>>(pts, occ8);
    pack_kernel<<<OCC8_U128 / 256, 256, 0, stream>>>(
        (const ulonglong2*)occ8, pk);
    conv_kernel<<<CONV_BLOCKS, CTHR, 0, stream>>>(
        (const ulonglong2*)pk, W0, b0, W1, b1, (float4*)d_out);
}